// Round 2
// baseline (470.495 us; speedup 1.0000x reference)
//
#include <hip/hip_runtime.h>
#include <math.h>

// ---------------------------------------------------------------------------
// UnitGCN (AGCN block) forward.  N=64, C=OC=64, T=300, V=25, S=3, IC=16.
//   Partial-sum path (ws >= 12.48 MB):
//     K1: grid(25,64)x256: embed+scores as before, but each block STORES its
//         3x25x25 partial into part[ts][n][...] (no atomics, no K0).
//     K2r: grid(3,64)x256: sum 25 partials -> /4800 -> softmax(v) -> +A+PA.
//   Fallback (small ws): K0 zero + K1 atomicAdd + K2 legacy (verified path).
//   K3: grid(1280)x256: XCD-grouped swizzle (all 20 t-chunks of one n on one
//       XCD -> boundary write-line merge in that L2); 15 t per block = exactly
//       5 blocks/CU, no tail; A-frags prefetched 2 phases ahead, residuals 1
//       phase ahead; nontemporal out stores (keep x L3-resident);
//       P_s = Xt@att_s (MFMA) -> dbuf LDS transpose -> Z = [wd]@Pcat ->
//       fused BN+fp32-residual+ReLU.
// MFMA convention (HW-verified m89/m91): D[m][n] = sum_k A_lane(m)[k]*B_lane(n)[k],
//   frag row = lane&15, k = (lane>>4)*8 + j ; C/D: col = lane&15, row = (lane>>4)*4+r.
// ---------------------------------------------------------------------------

typedef short  short4v  __attribute__((ext_vector_type(4)));
typedef short  short8v  __attribute__((ext_vector_type(8)));
typedef float  float4v  __attribute__((ext_vector_type(4)));

#define MFMA_BF16(a,b,c) __builtin_amdgcn_mfma_f32_16x16x32_bf16((a),(b),(c),0,0,0)

__device__ __forceinline__ unsigned short f2bf(float f) {
  union { float f; unsigned int u; } v; v.f = f;
  unsigned int r = v.u + 0x7FFFu + ((v.u >> 16) & 1u);   // RNE
  return (unsigned short)(r >> 16);
}
__device__ __forceinline__ unsigned pack2bf(float a, float b) {
#if __has_builtin(__builtin_amdgcn_cvt_pk_bf16_f32)
  typedef __bf16 bf2_t __attribute__((ext_vector_type(2)));
  bf2_t p = __builtin_amdgcn_cvt_pk_bf16_f32(a, b);
  union { bf2_t v; unsigned u; } c; c.v = p; return c.u;
#else
  return (unsigned)f2bf(a) | ((unsigned)f2bf(b) << 16);
#endif
}
__device__ __forceinline__ short8v pk8(const float* f) {
  union { unsigned u[4]; short8v s; } c;
  c.u[0] = pack2bf(f[0], f[1]); c.u[1] = pack2bf(f[2], f[3]);
  c.u[2] = pack2bf(f[4], f[5]); c.u[3] = pack2bf(f[6], f[7]);
  return c.s;
}
// 8 bf16 from LDS via two ds_read_b64 (rows 8B-aligned)
__device__ __forceinline__ short8v ld8_b64(const unsigned short* p) {
  short4v a = *(const short4v*)p;
  short4v b = *(const short4v*)(p + 4);
  short8v r;
  r[0]=a[0]; r[1]=a[1]; r[2]=a[2]; r[3]=a[3];
  r[4]=b[0]; r[5]=b[1]; r[6]=b[2]; r[7]=b[3];
  return r;
}

// ============================ K0: zero scores ===============================
__global__ __launch_bounds__(256) void k0_zero(float* __restrict__ p, int nelem) {
  int i = blockIdx.x * 256 + threadIdx.x;
  if (i < nelem) p[i] = 0.f;
}

// ============================ K1: attention scores ==========================
// grid (25, 64) x 256 thr (4 waves). 12 t per block, 2 chunks of 6 t.
// use_atomic=1: atomicAdd into scores (needs K0).  use_atomic=0: store the
// block's partial into part[ts][n][s][v][u] (no atomics).
__global__ __launch_bounds__(256) void k1_scores(
    const float* __restrict__ x,  const float* __restrict__ wa,
    const float* __restrict__ ba, const float* __restrict__ wb,
    const float* __restrict__ bb, float* __restrict__ scores,
    float* __restrict__ part,     int use_atomic)
{
  __shared__ __align__(16) unsigned short ET[3][160*40]; // [s][tv][krow] bf16
  const unsigned tid  = threadIdx.x;
  const unsigned lane = tid & 63u, w = tid >> 6;
  const unsigned l15  = lane & 15u, q = lane >> 4;
  const unsigned n = blockIdx.y, ts = blockIdx.x;
  const unsigned t0 = ts * 12u;
  const float* xn = x + (size_t)n * 480000;

  // W fragments in registers: A[m=krow][k=c]; mt=0 -> wa rows, mt=1 -> wb rows
  short8v Wf[3][2][2];
  #pragma unroll
  for (int s = 0; s < 3; ++s)
    #pragma unroll
    for (int mt = 0; mt < 2; ++mt)
      #pragma unroll
      for (int ks = 0; ks < 2; ++ks) {
        const float* src = (mt ? wb : wa) + ((size_t)s*16 + l15)*64
                         + (unsigned)ks*32 + q*8;
        float tf[8];
        #pragma unroll
        for (int j = 0; j < 8; ++j) tf[j] = src[j];
        Wf[s][mt][ks] = pk8(tf);
      }
  // bias in registers: output row = mt*16 + q*4 + r
  float bias[3][2][4];
  #pragma unroll
  for (int s = 0; s < 3; ++s)
    #pragma unroll
    for (int mt = 0; mt < 2; ++mt)
      #pragma unroll
      for (int r = 0; r < 4; ++r)
        bias[s][mt][r] = (mt ? bb : ba)[s*16 + q*4 + (unsigned)r];

  float4v acc[3];
  #pragma unroll
  for (int j = 0; j < 3; ++j) acc[j] = (float4v){0.f,0.f,0.f,0.f};

  for (unsigned ch = 0; ch < 2; ++ch) {            // 2 chunks of 6 t
    const unsigned tvbase = (t0 + ch*6u) * 25u;
    if (ch) __syncthreads();                       // prev chunk's reads done
    // ---- embed: tiles w, w+4, w+8 (10 tiles over 4 waves) ----
    for (unsigned nn = 0; nn < 3; ++nn) {
      unsigned nt = w + 4*nn;
      if (nt < 10) {
        unsigned tvb = nt*16 + l15;
        unsigned tvg = tvbase + tvb;
        if (tvg > 7499u) tvg = 7499u;              // clamp; values discarded
        const float* p = xn + (size_t)q*60000 + tvg;   // c = q*8 base
        float xa[8], xb[8];
        #pragma unroll
        for (int j = 0; j < 8; ++j) {
          xa[j] = p[(size_t)j*7500];
          xb[j] = p[240000 + (size_t)j*7500];
        }
        short8v B0 = pk8(xa), B1 = pk8(xb);
        #pragma unroll
        for (int s = 0; s < 3; ++s)
          #pragma unroll
          for (int mt = 0; mt < 2; ++mt) {
            float4v d = (float4v){0.f,0.f,0.f,0.f};
            d = MFMA_BF16(Wf[s][mt][0], B0, d);
            d = MFMA_BF16(Wf[s][mt][1], B1, d);
            unsigned krb = (unsigned)mt*16 + q*4;
            uint2 pk2;
            pk2.x = pack2bf(d[0] + bias[s][mt][0], d[1] + bias[s][mt][1]);
            pk2.y = pack2bf(d[2] + bias[s][mt][2], d[3] + bias[s][mt][3]);
            *(uint2*)(&ET[s][tvb*40 + krb]) = pk2;
          }
      }
    }
    __syncthreads();
    // ---- scores: D[v][u] += sum_{t,k} Ea[k][t*25+v]*Eb[k][t*25+u] ----
    #pragma unroll
    for (int j = 0; j < 3; ++j) {
      unsigned g = (unsigned)j*4 + w;              // 12 (s,mt,nt2) tasks / 4 waves
      unsigned s = g >> 2, mt = (g >> 1) & 1u, nt2 = g & 1u;
      #pragma unroll
      for (int ks = 0; ks < 3; ++ks) {
        unsigned t    = 2*ks + (q >> 1);
        unsigned kofs = 8*(q & 1u);
        short8v Af = *(const short8v*)(&ET[s][(t*25 + mt*16  + l15)*40 + kofs]);
        short8v Bf = *(const short8v*)(&ET[s][(t*25 + nt2*16 + l15)*40 + 16 + kofs]);
        acc[j] = MFMA_BF16(Af, Bf, acc[j]);
      }
    }
  }
  // ---- write out: atomic accumulate OR per-block partial slab ----
  if (use_atomic) {
    #pragma unroll
    for (int j = 0; j < 3; ++j) {
      unsigned g = (unsigned)j*4 + w;
      unsigned s = g >> 2, mt = (g >> 1) & 1u, nt2 = g & 1u;
      unsigned u = nt2*16 + l15;
      if (u < 25) {
        #pragma unroll
        for (int r = 0; r < 4; ++r) {
          unsigned v = mt*16 + q*4 + (unsigned)r;
          if (v < 25)
            atomicAdd(&scores[(size_t)n*1875 + s*625 + v*25 + u], acc[j][r]);
        }
      }
    }
  } else {
    float* slab = part + ((size_t)ts*64u + n)*1875u;
    #pragma unroll
    for (int j = 0; j < 3; ++j) {
      unsigned g = (unsigned)j*4 + w;
      unsigned s = g >> 2, mt = (g >> 1) & 1u, nt2 = g & 1u;
      unsigned u = nt2*16 + l15;
      if (u < 25) {
        #pragma unroll
        for (int r = 0; r < 4; ++r) {
          unsigned v = mt*16 + q*4 + (unsigned)r;
          if (v < 25)
            slab[s*625u + v*25u + u] = acc[j][r];
        }
      }
    }
  }
}

// ====================== K2 legacy: softmax(v) + A + PA ======================
// grid (3, 64): one block per (s, n). 64 threads. (atomic-path fallback)
__global__ __launch_bounds__(64) void k2_softmax(
    const float* __restrict__ scores, const float* __restrict__ A,
    const float* __restrict__ PA, float* __restrict__ att)
{
  const unsigned tid = threadIdx.x, s = blockIdx.x, n = blockIdx.y;
  if (tid >= 25) return;
  const unsigned u = tid;
  float col[25];
  float m = -1e30f;
  #pragma unroll
  for (int v = 0; v < 25; ++v) {
    col[v] = scores[(size_t)n*1875 + s*625 + (unsigned)v*25 + u] * (1.f/4800.f);
    m = fmaxf(m, col[v]);
  }
  float S = 0.f;
  #pragma unroll
  for (int v = 0; v < 25; ++v) { col[v] = expf(col[v] - m); S += col[v]; }
  float inv = 1.f / S;
  #pragma unroll
  for (int v = 0; v < 25; ++v)
    att[(((size_t)n*3 + s)*25 + (unsigned)v)*25 + u] =
        col[v]*inv + A[s*625 + (unsigned)v*25 + u] + PA[s*625 + (unsigned)v*25 + u];
}

// ================= K2r: reduce 25 partials + softmax + A + PA ===============
// grid (3, 64) x 256 thr. Sum part[ts] slabs in LDS, then column softmax.
__global__ __launch_bounds__(256) void k2_softmax_r(
    const float* __restrict__ part, const float* __restrict__ A,
    const float* __restrict__ PA, float* __restrict__ att)
{
  __shared__ float sm[625];
  const unsigned tid = threadIdx.x, s = blockIdx.x, n = blockIdx.y;
  for (unsigned cell = tid; cell < 625u; cell += 256u) {
    float acc = 0.f;
    #pragma unroll
    for (int ts = 0; ts < 25; ++ts)
      acc += part[((size_t)ts*64u + n)*1875u + s*625u + cell];
    sm[cell] = acc;
  }
  __syncthreads();
  if (tid < 25) {
    const unsigned u = tid;
    float col[25];
    float m = -1e30f;
    #pragma unroll
    for (int v = 0; v < 25; ++v) {
      col[v] = sm[(unsigned)v*25 + u] * (1.f/4800.f);
      m = fmaxf(m, col[v]);
    }
    float S = 0.f;
    #pragma unroll
    for (int v = 0; v < 25; ++v) { col[v] = expf(col[v] - m); S += col[v]; }
    float inv = 1.f / S;
    #pragma unroll
    for (int v = 0; v < 25; ++v)
      att[(((size_t)n*3 + s)*25 + (unsigned)v)*25 + u] =
          col[v]*inv + A[s*625 + (unsigned)v*25 + u] + PA[s*625 + (unsigned)v*25 + u];
  }
}

// ============== K3: y = x@att, z = Wd_cat@Pcat, BN+ReLU+residual ============
// grid (1280) x 256 thr = 4 waves; wave = c/o tile. 15 t per block
// (exactly 5 blocks/CU).  XCD-grouped: all 20 ts-blocks of one n on one XCD.
// A-frags prefetched 2 t ahead, residuals 1 t ahead; nontemporal out stores.
__global__ __launch_bounds__(256, 4) void k3_main(
    const float* __restrict__ x,   const float* __restrict__ wd,
    const float* __restrict__ bd,  const float* __restrict__ gam,
    const float* __restrict__ bet, const float* __restrict__ mu,
    const float* __restrict__ var, const float* __restrict__ att,
    float* __restrict__ out)
{
  __shared__ __align__(16) unsigned short Pt[2][32*196];  // [buf][u][k=s*64+c]
  const unsigned tid  = threadIdx.x;
  const unsigned lane = tid & 63u, mt = tid >> 6;         // wave = c/o tile
  const unsigned l15  = lane & 15u, q = lane >> 4;
  // XCD-grouped swizzle: wgid%8 = XCD [m09]; keep one n's 20 blocks together.
  const unsigned wid = blockIdx.x;                        // 0..1279
  const unsigned xcd = wid & 7u, li = wid >> 3;           // li: 0..159
  const unsigned n   = xcd + 8u*(li/20u);
  const unsigned t0  = (li % 20u) * 15u;

  // BN consts in registers for this lane's 4 output rows o = mt*16+q*4+r
  float ksr[4], kbr[4];
  #pragma unroll
  for (int r = 0; r < 4; ++r) {
    unsigned o = mt*16 + q*4 + (unsigned)r;
    float sc = gam[o] * rsqrtf(var[o] + 1e-5f);
    ksr[r] = sc;
    kbr[r] = (bd[o] + bd[64+o] + bd[128+o] - mu[o]) * sc + bet[o];
  }
  // att^T B-frags in registers: B[n=u][k=v]; zeros for v>=25 (kills x garbage)
  short8v ATf[3][2];
  #pragma unroll
  for (int s = 0; s < 3; ++s)
    #pragma unroll
    for (int nt2 = 0; nt2 < 2; ++nt2) {
      unsigned u = (unsigned)nt2*16 + l15;
      float tf[8];
      #pragma unroll
      for (int j = 0; j < 8; ++j) {
        unsigned v = q*8 + (unsigned)j;
        tf[j] = (v < 25 && u < 25) ? att[(((size_t)n*3 + s)*25 + v)*25 + u] : 0.f;
      }
      ATf[s][nt2] = pk8(tf);
    }
  // wd A-frags in registers: A[m=o][k=c]
  short8v Awf[6];
  #pragma unroll
  for (int ks = 0; ks < 6; ++ks) {
    const float* src = wd + ((size_t)((unsigned)ks>>1)*64 + mt*16 + l15)*64
                     + ((unsigned)ks & 1u)*32 + q*8;
    float tf[8];
    #pragma unroll
    for (int j = 0; j < 8; ++j) tf[j] = src[j];
    Awf[ks] = pk8(tf);
  }
  // shared residual/output offsets: o*7500 + u  (fits u32)
  unsigned offs[2][4];
  const bool valid1 = (l15 < 9);                    // u=16+l15 < 25
  #pragma unroll
  for (int nt2 = 0; nt2 < 2; ++nt2)
    #pragma unroll
    for (int r = 0; r < 4; ++r)
      offs[nt2][r] = (mt*16 + q*4 + (unsigned)r)*7500u + (unsigned)nt2*16 + l15;

  const float* xn = x + (size_t)n * 480000;
  float*       on = (float*)out + (size_t)n * 480000;
  const float* xr = xn + (size_t)(mt*16 + l15)*7500;   // this lane's P A-row

  // ---- prologue: P(t0) -> Pt[0]; prefetch A(t0+1) + resid(t0) ----
  {
    const float* pa = xr + t0*25 + q*8;
    float fa[8];
    #pragma unroll
    for (int j = 0; j < 8; ++j) fa[j] = pa[j];
    short8v Ax = pk8(fa);
    #pragma unroll
    for (int s = 0; s < 3; ++s)
      #pragma unroll
      for (int nt2 = 0; nt2 < 2; ++nt2) {
        float4v d = (float4v){0.f,0.f,0.f,0.f};
        d = MFMA_BF16(Ax, ATf[s][nt2], d);
        unsigned u  = (unsigned)nt2*16 + l15;
        unsigned kb = (unsigned)s*64 + mt*16 + q*4;
        uint2 pk2; pk2.x = pack2bf(d[0], d[1]); pk2.y = pack2bf(d[2], d[3]);
        *(uint2*)(&Pt[0][u*196 + kb]) = pk2;
      }
  }
  float aN[8];                                      // A floats for t0+1
  {
    const float* pa = xr + t0*25 + 25 + q*8;
    #pragma unroll
    for (int j = 0; j < 8; ++j) aN[j] = pa[j];
  }
  float xvC[2][4];                                  // residual floats for t0
  #pragma unroll
  for (int nt2 = 0; nt2 < 2; ++nt2)
    if (nt2 == 0 || valid1) {
      #pragma unroll
      for (int r = 0; r < 4; ++r) xvC[nt2][r] = xn[offs[nt2][r] + t0*25];
    }

  #pragma unroll
  for (int t = 0; t < 15; ++t) {
    const unsigned cur = (unsigned)t & 1u, nxt = cur ^ 1u;
    const unsigned t25 = (t0 + (unsigned)t)*25u;
    __syncthreads();   // P(t) visible; Z(t-1) reads of Pt[nxt] done

    // ---- deep prefetch: A(t+2), resid(t+1) — overlap Z+P+epilogue ----
    const bool pfA = (t < 13);
    const bool pfR = (t < 14);
    float aP[8];
    float xvN[2][4];
    if (pfA) {
      const float* pa = xr + t25 + 50 + q*8;
      #pragma unroll
      for (int j = 0; j < 8; ++j) aP[j] = pa[j];
    }
    if (pfR) {
      #pragma unroll
      for (int nt2 = 0; nt2 < 2; ++nt2)
        if (nt2 == 0 || valid1) {
          #pragma unroll
          for (int r = 0; r < 4; ++r) xvN[nt2][r] = xn[offs[nt2][r] + t25 + 25u];
        }
    }
    // ---- Z phase: Z[o][u] = sum_{s,c} wd[s][o][c]*P[s*64+c][u] ----
    float4v za = (float4v){0.f,0.f,0.f,0.f}, zb = (float4v){0.f,0.f,0.f,0.f};
    #pragma unroll
    for (int ks = 0; ks < 6; ++ks) {
      short8v B0 = ld8_b64(&Pt[cur][l15*196      + (unsigned)ks*32 + q*8]);
      short8v B1 = ld8_b64(&Pt[cur][(16+l15)*196 + (unsigned)ks*32 + q*8]);
      za = MFMA_BF16(Awf[ks], B0, za);
      zb = MFMA_BF16(Awf[ks], B1, zb);
    }
    // ---- P(t+1) -> Pt[nxt] (A floats prefetched 2 iters ago) ----
    if (t < 14) {
      short8v Ax = pk8(aN);
      #pragma unroll
      for (int s = 0; s < 3; ++s)
        #pragma unroll
        for (int nt2 = 0; nt2 < 2; ++nt2) {
          float4v d = (float4v){0.f,0.f,0.f,0.f};
          d = MFMA_BF16(Ax, ATf[s][nt2], d);
          unsigned u  = (unsigned)nt2*16 + l15;
          unsigned kb = (unsigned)s*64 + mt*16 + q*4;
          uint2 pk2; pk2.x = pack2bf(d[0], d[1]); pk2.y = pack2bf(d[2], d[3]);
          *(uint2*)(&Pt[nxt][u*196 + kb]) = pk2;
        }
    }
    // ---- epilogue: BN + fp32 residual + ReLU (nontemporal stores) ----
    #pragma unroll
    for (int nt2 = 0; nt2 < 2; ++nt2) {
      float4v zz = nt2 ? zb : za;
      if (nt2 == 0 || valid1) {
        #pragma unroll
        for (int r = 0; r < 4; ++r) {
          float val = zz[r]*ksr[r] + kbr[r] + xvC[nt2][r];
          __builtin_nontemporal_store(fmaxf(val, 0.f), &on[offs[nt2][r] + t25]);
        }
      }
    }
    // ---- rotate prefetch buffers ----
    if (pfA) {
      #pragma unroll
      for (int j = 0; j < 8; ++j) aN[j] = aP[j];
    }
    if (pfR) {
      #pragma unroll
      for (int nt2 = 0; nt2 < 2; ++nt2)
        #pragma unroll
        for (int r = 0; r < 4; ++r) xvC[nt2][r] = xvN[nt2][r];
    }
  }
}

// ================================ launcher ==================================
extern "C" void kernel_launch(void* const* d_in, const int* in_sizes, int n_in,
                              void* d_out, int out_size, void* d_ws, size_t ws_size,
                              hipStream_t stream)
{
  (void)in_sizes; (void)n_in; (void)out_size;
  const float* x   = (const float*)d_in[0];
  const float* A   = (const float*)d_in[1];
  const float* PA  = (const float*)d_in[2];
  const float* wa  = (const float*)d_in[3];
  const float* ba  = (const float*)d_in[4];
  const float* wb  = (const float*)d_in[5];
  const float* bb  = (const float*)d_in[6];
  const float* wd  = (const float*)d_in[7];
  const float* bd  = (const float*)d_in[8];
  const float* gam = (const float*)d_in[9];
  const float* bet = (const float*)d_in[10];
  const float* mu  = (const float*)d_in[11];
  const float* var = (const float*)d_in[12];
  float* out = (float*)d_out;

  const size_t NEED = (size_t)(25*120000 + 120000) * sizeof(float);  // 12.48 MB
  if (ws_size >= NEED) {
    // -------- partial-sum path: no atomics, no K0 --------
    float* part = (float*)d_ws;              // 25 * 64 * 1875 = 3,000,000 f32
    float* att  = part + 3000000;            // 64*3*625 = 120,000 f32
    hipLaunchKernelGGL(k1_scores, dim3(25, 64), dim3(256), 0, stream,
                       x, wa, ba, wb, bb, part, part, 0);
    hipLaunchKernelGGL(k2_softmax_r, dim3(3, 64), dim3(256), 0, stream,
                       part, A, PA, att);
    hipLaunchKernelGGL(k3_main, dim3(1280), dim3(256), 0, stream,
                       x, wd, bd, gam, bet, mu, var, att, out);
  } else {
    // -------- fallback: verified atomic path --------
    float* scores = (float*)d_ws;            // 120,000 f32
    float* att    = scores + 120000;         // 120,000 f32
    hipLaunchKernelGGL(k0_zero, dim3((120000 + 255)/256), dim3(256), 0, stream,
                       scores, 120000);
    hipLaunchKernelGGL(k1_scores, dim3(25, 64), dim3(256), 0, stream,
                       x, wa, ba, wb, bb, scores, scores, 1);
    hipLaunchKernelGGL(k2_softmax, dim3(3, 64), dim3(64), 0, stream,
                       scores, A, PA, att);
    hipLaunchKernelGGL(k3_main, dim3(1280), dim3(256), 0, stream,
                       x, wd, bd, gam, bet, mu, var, att, out);
  }
}

// Round 3
// 362.762 us; speedup vs baseline: 1.2970x; 1.2970x over previous
//
#include <hip/hip_runtime.h>
#include <math.h>

// ---------------------------------------------------------------------------
// UnitGCN (AGCN block) forward.  N=64, C=OC=64, T=300, V=25, S=3, IC=16.
//   Partial-sum path (ws >= 12.48 MB):
//     K1: grid(25,64)x256: embed E=[wa;wb]@X via MFMA; scores partial per
//         block stored to part[ts][n][...] (no atomics, no K0).
//     K2r: grid(3,64)x256: sum 25 partials -> /4800 -> softmax(v) -> +A+PA.
//   Fallback (small ws): K0 zero + K1 atomicAdd + K2 legacy.
//   K3 (round-1 structure, 15-t tiles): grid(1280)x256, n=wid/20, t0=(wid%20)*15
//       = exactly 5 blocks/CU, no tail. wd/att^T frags + BN consts in regs;
//       x A-frags direct from global (1-ahead prefetch); P_s = Xt@att_s (MFMA);
//       double-buffered Pt LDS transpose (1 barrier/t); Z = [wd]@Pcat;
//       fused BN+fp32-residual+ReLU with PLAIN stores (L2 write-merge).
//   NOTE (round-2 lesson): XCD-grouped swizzle thrashed L2 (FETCH 94->264 MB)
//   and nontemporal stores broke write-merging (WRITE 171->296 MB). Reverted.
// MFMA convention (HW-verified m89/m91): D[m][n] = sum_k A_lane(m)[k]*B_lane(n)[k],
//   frag row = lane&15, k = (lane>>4)*8 + j ; C/D: col = lane&15, row = (lane>>4)*4+r.
// ---------------------------------------------------------------------------

typedef short  short4v  __attribute__((ext_vector_type(4)));
typedef short  short8v  __attribute__((ext_vector_type(8)));
typedef float  float4v  __attribute__((ext_vector_type(4)));

#define MFMA_BF16(a,b,c) __builtin_amdgcn_mfma_f32_16x16x32_bf16((a),(b),(c),0,0,0)

__device__ __forceinline__ unsigned short f2bf(float f) {
  union { float f; unsigned int u; } v; v.f = f;
  unsigned int r = v.u + 0x7FFFu + ((v.u >> 16) & 1u);   // RNE
  return (unsigned short)(r >> 16);
}
__device__ __forceinline__ unsigned pack2bf(float a, float b) {
#if __has_builtin(__builtin_amdgcn_cvt_pk_bf16_f32)
  typedef __bf16 bf2_t __attribute__((ext_vector_type(2)));
  bf2_t p = __builtin_amdgcn_cvt_pk_bf16_f32(a, b);
  union { bf2_t v; unsigned u; } c; c.v = p; return c.u;
#else
  return (unsigned)f2bf(a) | ((unsigned)f2bf(b) << 16);
#endif
}
__device__ __forceinline__ short8v pk8(const float* f) {
  union { unsigned u[4]; short8v s; } c;
  c.u[0] = pack2bf(f[0], f[1]); c.u[1] = pack2bf(f[2], f[3]);
  c.u[2] = pack2bf(f[4], f[5]); c.u[3] = pack2bf(f[6], f[7]);
  return c.s;
}
// 8 bf16 from LDS via two ds_read_b64 (rows 8B-aligned)
__device__ __forceinline__ short8v ld8_b64(const unsigned short* p) {
  short4v a = *(const short4v*)p;
  short4v b = *(const short4v*)(p + 4);
  short8v r;
  r[0]=a[0]; r[1]=a[1]; r[2]=a[2]; r[3]=a[3];
  r[4]=b[0]; r[5]=b[1]; r[6]=b[2]; r[7]=b[3];
  return r;
}

// ============================ K0: zero scores ===============================
__global__ __launch_bounds__(256) void k0_zero(float* __restrict__ p, int nelem) {
  int i = blockIdx.x * 256 + threadIdx.x;
  if (i < nelem) p[i] = 0.f;
}

// ============================ K1: attention scores ==========================
// grid (25, 64) x 256 thr (4 waves). 12 t per block, 2 chunks of 6 t.
// use_atomic=1: atomicAdd into scores (needs K0).  use_atomic=0: store the
// block's partial into part[ts][n][s][v][u] (no atomics).
__global__ __launch_bounds__(256) void k1_scores(
    const float* __restrict__ x,  const float* __restrict__ wa,
    const float* __restrict__ ba, const float* __restrict__ wb,
    const float* __restrict__ bb, float* __restrict__ scores,
    float* __restrict__ part,     int use_atomic)
{
  __shared__ __align__(16) unsigned short ET[3][160*40]; // [s][tv][krow] bf16
  const unsigned tid  = threadIdx.x;
  const unsigned lane = tid & 63u, w = tid >> 6;
  const unsigned l15  = lane & 15u, q = lane >> 4;
  const unsigned n = blockIdx.y, ts = blockIdx.x;
  const unsigned t0 = ts * 12u;
  const float* xn = x + (size_t)n * 480000;

  // W fragments in registers: A[m=krow][k=c]; mt=0 -> wa rows, mt=1 -> wb rows
  short8v Wf[3][2][2];
  #pragma unroll
  for (int s = 0; s < 3; ++s)
    #pragma unroll
    for (int mt = 0; mt < 2; ++mt)
      #pragma unroll
      for (int ks = 0; ks < 2; ++ks) {
        const float* src = (mt ? wb : wa) + ((size_t)s*16 + l15)*64
                         + (unsigned)ks*32 + q*8;
        float tf[8];
        #pragma unroll
        for (int j = 0; j < 8; ++j) tf[j] = src[j];
        Wf[s][mt][ks] = pk8(tf);
      }
  // bias in registers: output row = mt*16 + q*4 + r
  float bias[3][2][4];
  #pragma unroll
  for (int s = 0; s < 3; ++s)
    #pragma unroll
    for (int mt = 0; mt < 2; ++mt)
      #pragma unroll
      for (int r = 0; r < 4; ++r)
        bias[s][mt][r] = (mt ? bb : ba)[s*16 + q*4 + (unsigned)r];

  float4v acc[3];
  #pragma unroll
  for (int j = 0; j < 3; ++j) acc[j] = (float4v){0.f,0.f,0.f,0.f};

  for (unsigned ch = 0; ch < 2; ++ch) {            // 2 chunks of 6 t
    const unsigned tvbase = (t0 + ch*6u) * 25u;
    if (ch) __syncthreads();                       // prev chunk's reads done
    // ---- embed: tiles w, w+4, w+8 (10 tiles over 4 waves) ----
    for (unsigned nn = 0; nn < 3; ++nn) {
      unsigned nt = w + 4*nn;
      if (nt < 10) {
        unsigned tvb = nt*16 + l15;
        unsigned tvg = tvbase + tvb;
        if (tvg > 7499u) tvg = 7499u;              // clamp; values discarded
        const float* p = xn + (size_t)q*60000 + tvg;   // c = q*8 base
        float xa[8], xb[8];
        #pragma unroll
        for (int j = 0; j < 8; ++j) {
          xa[j] = p[(size_t)j*7500];
          xb[j] = p[240000 + (size_t)j*7500];
        }
        short8v B0 = pk8(xa), B1 = pk8(xb);
        #pragma unroll
        for (int s = 0; s < 3; ++s)
          #pragma unroll
          for (int mt = 0; mt < 2; ++mt) {
            float4v d = (float4v){0.f,0.f,0.f,0.f};
            d = MFMA_BF16(Wf[s][mt][0], B0, d);
            d = MFMA_BF16(Wf[s][mt][1], B1, d);
            unsigned krb = (unsigned)mt*16 + q*4;
            uint2 pk2;
            pk2.x = pack2bf(d[0] + bias[s][mt][0], d[1] + bias[s][mt][1]);
            pk2.y = pack2bf(d[2] + bias[s][mt][2], d[3] + bias[s][mt][3]);
            *(uint2*)(&ET[s][tvb*40 + krb]) = pk2;
          }
      }
    }
    __syncthreads();
    // ---- scores: D[v][u] += sum_{t,k} Ea[k][t*25+v]*Eb[k][t*25+u] ----
    #pragma unroll
    for (int j = 0; j < 3; ++j) {
      unsigned g = (unsigned)j*4 + w;              // 12 (s,mt,nt2) tasks / 4 waves
      unsigned s = g >> 2, mt = (g >> 1) & 1u, nt2 = g & 1u;
      #pragma unroll
      for (int ks = 0; ks < 3; ++ks) {
        unsigned t    = 2*ks + (q >> 1);
        unsigned kofs = 8*(q & 1u);
        short8v Af = *(const short8v*)(&ET[s][(t*25 + mt*16  + l15)*40 + kofs]);
        short8v Bf = *(const short8v*)(&ET[s][(t*25 + nt2*16 + l15)*40 + 16 + kofs]);
        acc[j] = MFMA_BF16(Af, Bf, acc[j]);
      }
    }
  }
  // ---- write out: atomic accumulate OR per-block partial slab ----
  if (use_atomic) {
    #pragma unroll
    for (int j = 0; j < 3; ++j) {
      unsigned g = (unsigned)j*4 + w;
      unsigned s = g >> 2, mt = (g >> 1) & 1u, nt2 = g & 1u;
      unsigned u = nt2*16 + l15;
      if (u < 25) {
        #pragma unroll
        for (int r = 0; r < 4; ++r) {
          unsigned v = mt*16 + q*4 + (unsigned)r;
          if (v < 25)
            atomicAdd(&scores[(size_t)n*1875 + s*625 + v*25 + u], acc[j][r]);
        }
      }
    }
  } else {
    float* slab = part + ((size_t)ts*64u + n)*1875u;
    #pragma unroll
    for (int j = 0; j < 3; ++j) {
      unsigned g = (unsigned)j*4 + w;
      unsigned s = g >> 2, mt = (g >> 1) & 1u, nt2 = g & 1u;
      unsigned u = nt2*16 + l15;
      if (u < 25) {
        #pragma unroll
        for (int r = 0; r < 4; ++r) {
          unsigned v = mt*16 + q*4 + (unsigned)r;
          if (v < 25)
            slab[s*625u + v*25u + u] = acc[j][r];
        }
      }
    }
  }
}

// ====================== K2 legacy: softmax(v) + A + PA ======================
// grid (3, 64): one block per (s, n). 64 threads. (atomic-path fallback)
__global__ __launch_bounds__(64) void k2_softmax(
    const float* __restrict__ scores, const float* __restrict__ A,
    const float* __restrict__ PA, float* __restrict__ att)
{
  const unsigned tid = threadIdx.x, s = blockIdx.x, n = blockIdx.y;
  if (tid >= 25) return;
  const unsigned u = tid;
  float col[25];
  float m = -1e30f;
  #pragma unroll
  for (int v = 0; v < 25; ++v) {
    col[v] = scores[(size_t)n*1875 + s*625 + (unsigned)v*25 + u] * (1.f/4800.f);
    m = fmaxf(m, col[v]);
  }
  float S = 0.f;
  #pragma unroll
  for (int v = 0; v < 25; ++v) { col[v] = expf(col[v] - m); S += col[v]; }
  float inv = 1.f / S;
  #pragma unroll
  for (int v = 0; v < 25; ++v)
    att[(((size_t)n*3 + s)*25 + (unsigned)v)*25 + u] =
        col[v]*inv + A[s*625 + (unsigned)v*25 + u] + PA[s*625 + (unsigned)v*25 + u];
}

// ================= K2r: reduce 25 partials + softmax + A + PA ===============
// grid (3, 64) x 256 thr. Sum part[ts] slabs in LDS, then column softmax.
__global__ __launch_bounds__(256) void k2_softmax_r(
    const float* __restrict__ part, const float* __restrict__ A,
    const float* __restrict__ PA, float* __restrict__ att)
{
  __shared__ float sm[625];
  const unsigned tid = threadIdx.x, s = blockIdx.x, n = blockIdx.y;
  for (unsigned cell = tid; cell < 625u; cell += 256u) {
    float acc = 0.f;
    #pragma unroll
    for (int ts = 0; ts < 25; ++ts)
      acc += part[((size_t)ts*64u + n)*1875u + s*625u + cell];
    sm[cell] = acc;
  }
  __syncthreads();
  if (tid < 25) {
    const unsigned u = tid;
    float col[25];
    float m = -1e30f;
    #pragma unroll
    for (int v = 0; v < 25; ++v) {
      col[v] = sm[(unsigned)v*25 + u] * (1.f/4800.f);
      m = fmaxf(m, col[v]);
    }
    float S = 0.f;
    #pragma unroll
    for (int v = 0; v < 25; ++v) { col[v] = expf(col[v] - m); S += col[v]; }
    float inv = 1.f / S;
    #pragma unroll
    for (int v = 0; v < 25; ++v)
      att[(((size_t)n*3 + s)*25 + (unsigned)v)*25 + u] =
          col[v]*inv + A[s*625 + (unsigned)v*25 + u] + PA[s*625 + (unsigned)v*25 + u];
  }
}

// ============== K3: y = x@att, z = Wd_cat@Pcat, BN+ReLU+residual ============
// grid (1280) x 256 thr = 4 waves; wave = c/o tile. 15 t per block = exactly
// 5 blocks/CU, no tail. n = wid/20 (keeps one n's chunks consecutive in
// dispatch order, like round-1's (30,64) grid). Round-1 pipeline: 1-ahead
// A-frag prefetch, dbuf Pt, one barrier per t, PLAIN stores.
__global__ __launch_bounds__(256) void k3_main(
    const float* __restrict__ x,   const float* __restrict__ wd,
    const float* __restrict__ bd,  const float* __restrict__ gam,
    const float* __restrict__ bet, const float* __restrict__ mu,
    const float* __restrict__ var, const float* __restrict__ att,
    float* __restrict__ out)
{
  __shared__ __align__(16) unsigned short Pt[2][32*196];  // [buf][u][k=s*64+c]
  const unsigned tid  = threadIdx.x;
  const unsigned lane = tid & 63u, mt = tid >> 6;         // wave = c/o tile
  const unsigned l15  = lane & 15u, q = lane >> 4;
  const unsigned wid = blockIdx.x;                        // 0..1279
  const unsigned n   = wid / 20u;
  const unsigned t0  = (wid % 20u) * 15u;

  // BN consts in registers for this lane's 4 output rows o = mt*16+q*4+r
  float ksr[4], kbr[4];
  #pragma unroll
  for (int r = 0; r < 4; ++r) {
    unsigned o = mt*16 + q*4 + (unsigned)r;
    float sc = gam[o] * rsqrtf(var[o] + 1e-5f);
    ksr[r] = sc;
    kbr[r] = (bd[o] + bd[64+o] + bd[128+o] - mu[o]) * sc + bet[o];
  }
  // att^T B-frags in registers: B[n=u][k=v]; zeros for v>=25 (kills x garbage)
  short8v ATf[3][2];
  #pragma unroll
  for (int s = 0; s < 3; ++s)
    #pragma unroll
    for (int nt2 = 0; nt2 < 2; ++nt2) {
      unsigned u = (unsigned)nt2*16 + l15;
      float tf[8];
      #pragma unroll
      for (int j = 0; j < 8; ++j) {
        unsigned v = q*8 + (unsigned)j;
        tf[j] = (v < 25 && u < 25) ? att[(((size_t)n*3 + s)*25 + v)*25 + u] : 0.f;
      }
      ATf[s][nt2] = pk8(tf);
    }
  // wd A-frags in registers: A[m=o][k=c]
  short8v Awf[6];
  #pragma unroll
  for (int ks = 0; ks < 6; ++ks) {
    const float* src = wd + ((size_t)((unsigned)ks>>1)*64 + mt*16 + l15)*64
                     + ((unsigned)ks & 1u)*32 + q*8;
    float tf[8];
    #pragma unroll
    for (int j = 0; j < 8; ++j) tf[j] = src[j];
    Awf[ks] = pk8(tf);
  }
  // shared residual/output offsets: o*7500 + u  (fits u32)
  unsigned offs[2][4];
  const bool valid1 = (l15 < 9);                    // u=16+l15 < 25
  #pragma unroll
  for (int nt2 = 0; nt2 < 2; ++nt2)
    #pragma unroll
    for (int r = 0; r < 4; ++r)
      offs[nt2][r] = (mt*16 + q*4 + (unsigned)r)*7500u + (unsigned)nt2*16 + l15;

  const float* xn = x + (size_t)n * 480000;
  float*       on = (float*)out + (size_t)n * 480000;
  const float* xr = xn + (size_t)(mt*16 + l15)*7500;   // this lane's P A-row

  // ---- prologue: P(t0) -> Pt[0] ----
  {
    const float* pa = xr + t0*25 + q*8;              // max idx 7313 < 7500
    float fa[8];
    #pragma unroll
    for (int j = 0; j < 8; ++j) fa[j] = pa[j];
    short8v Ax = pk8(fa);
    #pragma unroll
    for (int s = 0; s < 3; ++s)
      #pragma unroll
      for (int nt2 = 0; nt2 < 2; ++nt2) {
        float4v d = (float4v){0.f,0.f,0.f,0.f};
        d = MFMA_BF16(Ax, ATf[s][nt2], d);
        unsigned u  = (unsigned)nt2*16 + l15;
        unsigned kb = (unsigned)s*64 + mt*16 + q*4;
        uint2 pk2; pk2.x = pack2bf(d[0], d[1]); pk2.y = pack2bf(d[2], d[3]);
        *(uint2*)(&Pt[0][u*196 + kb]) = pk2;
      }
  }

  for (unsigned t = 0; t < 15; ++t) {
    const unsigned cur = t & 1u, nxt = cur ^ 1u;
    const unsigned tg = t0 + t, t25 = tg*25;
    __syncthreads();   // P(t) visible; Z(t-1) reads of Pt[nxt] done

    // ---- next A-frag loads early (overlap Z) ----
    const bool hasnext = (t + 1u < 15u);
    short8v Axn;
    if (hasnext) {
      const float* pa = xr + t25 + 25 + q*8;
      float fa[8];
      #pragma unroll
      for (int j = 0; j < 8; ++j) fa[j] = pa[j];
      Axn = pk8(fa);
    }
    // ---- residual loads early ----
    float xv[2][4];
    #pragma unroll
    for (int nt2 = 0; nt2 < 2; ++nt2)
      if (nt2 == 0 || valid1) {
        #pragma unroll
        for (int r = 0; r < 4; ++r) xv[nt2][r] = xn[offs[nt2][r] + t25];
      }
    // ---- Z phase: Z[o][u] = sum_{s,c} wd[s][o][c]*P[s*64+c][u] ----
    float4v za = (float4v){0.f,0.f,0.f,0.f}, zb = (float4v){0.f,0.f,0.f,0.f};
    #pragma unroll
    for (int ks = 0; ks < 6; ++ks) {
      short8v B0 = ld8_b64(&Pt[cur][l15*196      + (unsigned)ks*32 + q*8]);
      short8v B1 = ld8_b64(&Pt[cur][(16+l15)*196 + (unsigned)ks*32 + q*8]);
      za = MFMA_BF16(Awf[ks], B0, za);
      zb = MFMA_BF16(Awf[ks], B1, zb);
    }
    // ---- P(t+1) -> Pt[nxt] ----
    if (hasnext) {
      #pragma unroll
      for (int s = 0; s < 3; ++s)
        #pragma unroll
        for (int nt2 = 0; nt2 < 2; ++nt2) {
          float4v d = (float4v){0.f,0.f,0.f,0.f};
          d = MFMA_BF16(Axn, ATf[s][nt2], d);
          unsigned u  = (unsigned)nt2*16 + l15;
          unsigned kb = (unsigned)s*64 + mt*16 + q*4;
          uint2 pk2; pk2.x = pack2bf(d[0], d[1]); pk2.y = pack2bf(d[2], d[3]);
          *(uint2*)(&Pt[nxt][u*196 + kb]) = pk2;
        }
    }
    // ---- epilogue: BN + fp32 residual + ReLU ----
    #pragma unroll
    for (int nt2 = 0; nt2 < 2; ++nt2) {
      float4v zz = nt2 ? zb : za;
      if (nt2 == 0 || valid1) {
        #pragma unroll
        for (int r = 0; r < 4; ++r) {
          float val = zz[r]*ksr[r] + kbr[r] + xv[nt2][r];
          on[offs[nt2][r] + t25] = fmaxf(val, 0.f);
        }
      }
    }
  }
}

// ================================ launcher ==================================
extern "C" void kernel_launch(void* const* d_in, const int* in_sizes, int n_in,
                              void* d_out, int out_size, void* d_ws, size_t ws_size,
                              hipStream_t stream)
{
  (void)in_sizes; (void)n_in; (void)out_size;
  const float* x   = (const float*)d_in[0];
  const float* A   = (const float*)d_in[1];
  const float* PA  = (const float*)d_in[2];
  const float* wa  = (const float*)d_in[3];
  const float* ba  = (const float*)d_in[4];
  const float* wb  = (const float*)d_in[5];
  const float* bb  = (const float*)d_in[6];
  const float* wd  = (const float*)d_in[7];
  const float* bd  = (const float*)d_in[8];
  const float* gam = (const float*)d_in[9];
  const float* bet = (const float*)d_in[10];
  const float* mu  = (const float*)d_in[11];
  const float* var = (const float*)d_in[12];
  float* out = (float*)d_out;

  const size_t NEED = (size_t)(25*120000 + 120000) * sizeof(float);  // 12.48 MB
  if (ws_size >= NEED) {
    // -------- partial-sum path: no atomics, no K0 --------
    float* part = (float*)d_ws;              // 25 * 64 * 1875 = 3,000,000 f32
    float* att  = part + 3000000;            // 64*3*625 = 120,000 f32
    hipLaunchKernelGGL(k1_scores, dim3(25, 64), dim3(256), 0, stream,
                       x, wa, ba, wb, bb, part, part, 0);
    hipLaunchKernelGGL(k2_softmax_r, dim3(3, 64), dim3(256), 0, stream,
                       part, A, PA, att);
    hipLaunchKernelGGL(k3_main, dim3(1280), dim3(256), 0, stream,
                       x, wd, bd, gam, bet, mu, var, att, out);
  } else {
    // -------- fallback: verified atomic path --------
    float* scores = (float*)d_ws;            // 120,000 f32
    float* att    = scores + 120000;         // 120,000 f32
    hipLaunchKernelGGL(k0_zero, dim3((120000 + 255)/256), dim3(256), 0, stream,
                       scores, 120000);
    hipLaunchKernelGGL(k1_scores, dim3(25, 64), dim3(256), 0, stream,
                       x, wa, ba, wb, bb, scores, scores, 1);
    hipLaunchKernelGGL(k2_softmax, dim3(3, 64), dim3(64), 0, stream,
                       scores, A, PA, att);
    hipLaunchKernelGGL(k3_main, dim3(1280), dim3(256), 0, stream,
                       x, wd, bd, gam, bet, mu, var, att, out);
  }
}

// Round 5
// 339.783 us; speedup vs baseline: 1.3847x; 1.0676x over previous
//
#include <hip/hip_runtime.h>
#include <math.h>

// ---------------------------------------------------------------------------
// UnitGCN (AGCN block) forward.  N=64, C=OC=64, T=300, V=25, S=3, IC=16.
//   Partial-sum path (ws >= 12.48 MB):
//     K1: grid(25,64)x256: embed E=[wa;wb]@X via MFMA; scores partial per
//         block stored to part[ts][n][...] (no atomics, no K0).
//     K2r: grid(3,64)x256: sum 25 partials -> /4800 -> softmax(v) -> +A+PA.
//   Fallback (small ws): K0 zero + K1 atomicAdd + K2 legacy.
//   K3: grid(25,64)x256, 12 t per block. wd/att^T frags + BN consts in regs;
//       x A-frags direct from global (1-ahead prefetch); P_s = Xt@att_s (MFMA);
//       dbuf Pt LDS transpose (1 barrier/t); Z = [wd]@Pcat; BN+residual+ReLU
//       into LDS obuf (f32), flushed every 4 t as full-line float4 sweeps
//       (fixes 1.4x write amplification + RMW fetches seen in rounds 1-3:
//       100 B row stores -> partial 128 B lines -> WRITE 172 MB vs 123 ideal).
//   NOTE (round-2 lesson): XCD-grouped swizzle thrashed L2 (FETCH 94->264 MB)
//   and nontemporal stores broke write-merging (WRITE 171->296 MB). Reverted.
// MFMA convention (HW-verified m89/m91): D[m][n] = sum_k A_lane(m)[k]*B_lane(n)[k],
//   frag row = lane&15, k = (lane>>4)*8 + j ; C/D: col = lane&15, row = (lane>>4)*4+r.
// ---------------------------------------------------------------------------

typedef short  short4v  __attribute__((ext_vector_type(4)));
typedef short  short8v  __attribute__((ext_vector_type(8)));
typedef float  float4v  __attribute__((ext_vector_type(4)));

#define MFMA_BF16(a,b,c) __builtin_amdgcn_mfma_f32_16x16x32_bf16((a),(b),(c),0,0,0)

__device__ __forceinline__ unsigned short f2bf(float f) {
  union { float f; unsigned int u; } v; v.f = f;
  unsigned int r = v.u + 0x7FFFu + ((v.u >> 16) & 1u);   // RNE
  return (unsigned short)(r >> 16);
}
__device__ __forceinline__ unsigned pack2bf(float a, float b) {
#if __has_builtin(__builtin_amdgcn_cvt_pk_bf16_f32)
  typedef __bf16 bf2_t __attribute__((ext_vector_type(2)));
  bf2_t p = __builtin_amdgcn_cvt_pk_bf16_f32(a, b);
  union { bf2_t v; unsigned u; } c; c.v = p; return c.u;
#else
  return (unsigned)f2bf(a) | ((unsigned)f2bf(b) << 16);
#endif
}
__device__ __forceinline__ short8v pk8(const float* f) {
  union { unsigned u[4]; short8v s; } c;
  c.u[0] = pack2bf(f[0], f[1]); c.u[1] = pack2bf(f[2], f[3]);
  c.u[2] = pack2bf(f[4], f[5]); c.u[3] = pack2bf(f[6], f[7]);
  return c.s;
}
// 8 bf16 from LDS via two ds_read_b64 (rows 8B-aligned)
__device__ __forceinline__ short8v ld8_b64(const unsigned short* p) {
  short4v a = *(const short4v*)p;
  short4v b = *(const short4v*)(p + 4);
  short8v r;
  r[0]=a[0]; r[1]=a[1]; r[2]=a[2]; r[3]=a[3];
  r[4]=b[0]; r[5]=b[1]; r[6]=b[2]; r[7]=b[3];
  return r;
}

// ============================ K0: zero scores ===============================
__global__ __launch_bounds__(256) void k0_zero(float* __restrict__ p, int nelem) {
  int i = blockIdx.x * 256 + threadIdx.x;
  if (i < nelem) p[i] = 0.f;
}

// ============================ K1: attention scores ==========================
// grid (25, 64) x 256 thr (4 waves). 12 t per block, 2 chunks of 6 t.
// use_atomic=1: atomicAdd into scores (needs K0).  use_atomic=0: store the
// block's partial into part[ts][n][s][v][u] (no atomics).
__global__ __launch_bounds__(256) void k1_scores(
    const float* __restrict__ x,  const float* __restrict__ wa,
    const float* __restrict__ ba, const float* __restrict__ wb,
    const float* __restrict__ bb, float* __restrict__ scores,
    float* __restrict__ part,     int use_atomic)
{
  __shared__ __align__(16) unsigned short ET[3][160*40]; // [s][tv][krow] bf16
  const unsigned tid  = threadIdx.x;
  const unsigned lane = tid & 63u, w = tid >> 6;
  const unsigned l15  = lane & 15u, q = lane >> 4;
  const unsigned n = blockIdx.y, ts = blockIdx.x;
  const unsigned t0 = ts * 12u;
  const float* xn = x + (size_t)n * 480000;

  // W fragments in registers: A[m=krow][k=c]; mt=0 -> wa rows, mt=1 -> wb rows
  short8v Wf[3][2][2];
  #pragma unroll
  for (int s = 0; s < 3; ++s)
    #pragma unroll
    for (int mt = 0; mt < 2; ++mt)
      #pragma unroll
      for (int ks = 0; ks < 2; ++ks) {
        const float* src = (mt ? wb : wa) + ((size_t)s*16 + l15)*64
                         + (unsigned)ks*32 + q*8;
        float tf[8];
        #pragma unroll
        for (int j = 0; j < 8; ++j) tf[j] = src[j];
        Wf[s][mt][ks] = pk8(tf);
      }
  // bias in registers: output row = mt*16 + q*4 + r
  float bias[3][2][4];
  #pragma unroll
  for (int s = 0; s < 3; ++s)
    #pragma unroll
    for (int mt = 0; mt < 2; ++mt)
      #pragma unroll
      for (int r = 0; r < 4; ++r)
        bias[s][mt][r] = (mt ? bb : ba)[s*16 + q*4 + (unsigned)r];

  float4v acc[3];
  #pragma unroll
  for (int j = 0; j < 3; ++j) acc[j] = (float4v){0.f,0.f,0.f,0.f};

  for (unsigned ch = 0; ch < 2; ++ch) {            // 2 chunks of 6 t
    const unsigned tvbase = (t0 + ch*6u) * 25u;
    if (ch) __syncthreads();                       // prev chunk's reads done
    // ---- embed: tiles w, w+4, w+8 (10 tiles over 4 waves) ----
    for (unsigned nn = 0; nn < 3; ++nn) {
      unsigned nt = w + 4*nn;
      if (nt < 10) {
        unsigned tvb = nt*16 + l15;
        unsigned tvg = tvbase + tvb;
        if (tvg > 7499u) tvg = 7499u;              // clamp; values discarded
        const float* p = xn + (size_t)q*60000 + tvg;   // c = q*8 base
        float xa[8], xb[8];
        #pragma unroll
        for (int j = 0; j < 8; ++j) {
          xa[j] = p[(size_t)j*7500];
          xb[j] = p[240000 + (size_t)j*7500];
        }
        short8v B0 = pk8(xa), B1 = pk8(xb);
        #pragma unroll
        for (int s = 0; s < 3; ++s)
          #pragma unroll
          for (int mt = 0; mt < 2; ++mt) {
            float4v d = (float4v){0.f,0.f,0.f,0.f};
            d = MFMA_BF16(Wf[s][mt][0], B0, d);
            d = MFMA_BF16(Wf[s][mt][1], B1, d);
            unsigned krb = (unsigned)mt*16 + q*4;
            uint2 pk2;
            pk2.x = pack2bf(d[0] + bias[s][mt][0], d[1] + bias[s][mt][1]);
            pk2.y = pack2bf(d[2] + bias[s][mt][2], d[3] + bias[s][mt][3]);
            *(uint2*)(&ET[s][tvb*40 + krb]) = pk2;
          }
      }
    }
    __syncthreads();
    // ---- scores: D[v][u] += sum_{t,k} Ea[k][t*25+v]*Eb[k][t*25+u] ----
    #pragma unroll
    for (int j = 0; j < 3; ++j) {
      unsigned g = (unsigned)j*4 + w;              // 12 (s,mt,nt2) tasks / 4 waves
      unsigned s = g >> 2, mt = (g >> 1) & 1u, nt2 = g & 1u;
      #pragma unroll
      for (int ks = 0; ks < 3; ++ks) {
        unsigned t    = 2*ks + (q >> 1);
        unsigned kofs = 8*(q & 1u);
        short8v Af = *(const short8v*)(&ET[s][(t*25 + mt*16  + l15)*40 + kofs]);
        short8v Bf = *(const short8v*)(&ET[s][(t*25 + nt2*16 + l15)*40 + 16 + kofs]);
        acc[j] = MFMA_BF16(Af, Bf, acc[j]);
      }
    }
  }
  // ---- write out: atomic accumulate OR per-block partial slab ----
  if (use_atomic) {
    #pragma unroll
    for (int j = 0; j < 3; ++j) {
      unsigned g = (unsigned)j*4 + w;
      unsigned s = g >> 2, mt = (g >> 1) & 1u, nt2 = g & 1u;
      unsigned u = nt2*16 + l15;
      if (u < 25) {
        #pragma unroll
        for (int r = 0; r < 4; ++r) {
          unsigned v = mt*16 + q*4 + (unsigned)r;
          if (v < 25)
            atomicAdd(&scores[(size_t)n*1875 + s*625 + v*25 + u], acc[j][r]);
        }
      }
    }
  } else {
    float* slab = part + ((size_t)ts*64u + n)*1875u;
    #pragma unroll
    for (int j = 0; j < 3; ++j) {
      unsigned g = (unsigned)j*4 + w;
      unsigned s = g >> 2, mt = (g >> 1) & 1u, nt2 = g & 1u;
      unsigned u = nt2*16 + l15;
      if (u < 25) {
        #pragma unroll
        for (int r = 0; r < 4; ++r) {
          unsigned v = mt*16 + q*4 + (unsigned)r;
          if (v < 25)
            slab[s*625u + v*25u + u] = acc[j][r];
        }
      }
    }
  }
}

// ====================== K2 legacy: softmax(v) + A + PA ======================
// grid (3, 64): one block per (s, n). 64 threads. (atomic-path fallback)
__global__ __launch_bounds__(64) void k2_softmax(
    const float* __restrict__ scores, const float* __restrict__ A,
    const float* __restrict__ PA, float* __restrict__ att)
{
  const unsigned tid = threadIdx.x, s = blockIdx.x, n = blockIdx.y;
  if (tid >= 25) return;
  const unsigned u = tid;
  float col[25];
  float m = -1e30f;
  #pragma unroll
  for (int v = 0; v < 25; ++v) {
    col[v] = scores[(size_t)n*1875 + s*625 + (unsigned)v*25 + u] * (1.f/4800.f);
    m = fmaxf(m, col[v]);
  }
  float S = 0.f;
  #pragma unroll
  for (int v = 0; v < 25; ++v) { col[v] = expf(col[v] - m); S += col[v]; }
  float inv = 1.f / S;
  #pragma unroll
  for (int v = 0; v < 25; ++v)
    att[(((size_t)n*3 + s)*25 + (unsigned)v)*25 + u] =
        col[v]*inv + A[s*625 + (unsigned)v*25 + u] + PA[s*625 + (unsigned)v*25 + u];
}

// ================= K2r: reduce 25 partials + softmax + A + PA ===============
// grid (3, 64) x 256 thr. Sum part[ts] slabs in LDS, then column softmax.
__global__ __launch_bounds__(256) void k2_softmax_r(
    const float* __restrict__ part, const float* __restrict__ A,
    const float* __restrict__ PA, float* __restrict__ att)
{
  __shared__ float sm[625];
  const unsigned tid = threadIdx.x, s = blockIdx.x, n = blockIdx.y;
  for (unsigned cell = tid; cell < 625u; cell += 256u) {
    float acc = 0.f;
    #pragma unroll
    for (int ts = 0; ts < 25; ++ts)
      acc += part[((size_t)ts*64u + n)*1875u + s*625u + cell];
    sm[cell] = acc;
  }
  __syncthreads();
  if (tid < 25) {
    const unsigned u = tid;
    float col[25];
    float m = -1e30f;
    #pragma unroll
    for (int v = 0; v < 25; ++v) {
      col[v] = sm[(unsigned)v*25 + u] * (1.f/4800.f);
      m = fmaxf(m, col[v]);
    }
    float S = 0.f;
    #pragma unroll
    for (int v = 0; v < 25; ++v) { col[v] = expf(col[v] - m); S += col[v]; }
    float inv = 1.f / S;
    #pragma unroll
    for (int v = 0; v < 25; ++v)
      att[(((size_t)n*3 + s)*25 + (unsigned)v)*25 + u] =
          col[v]*inv + A[s*625 + (unsigned)v*25 + u] + PA[s*625 + (unsigned)v*25 + u];
  }
}

// ============== K3: y = x@att, z = Wd_cat@Pcat, BN+ReLU+residual ============
// grid (25,64) x 256 thr = 4 waves; wave mt owns output rows [mt*16,mt*16+16).
// 12 t per block. Round-1 pipeline (1-ahead A-frag prefetch, dbuf Pt, one
// barrier per t) + NEW: f32 obuf in LDS, flushed every 4 t as contiguous
// 400 B-per-c float4 sweeps (full-line writes; kills RMW amplification).
__global__ __launch_bounds__(256) void k3_main(
    const float* __restrict__ x,   const float* __restrict__ wd,
    const float* __restrict__ bd,  const float* __restrict__ gam,
    const float* __restrict__ bet, const float* __restrict__ mu,
    const float* __restrict__ var, const float* __restrict__ att,
    float* __restrict__ out)
{
  __shared__ __align__(16) unsigned short Pt[2][32*196];  // [buf][u][k=s*64+c]
  __shared__ __align__(16) float obuf[64*100];            // [c][4t*25v] f32
  const unsigned tid  = threadIdx.x;
  const unsigned lane = tid & 63u, mt = tid >> 6;         // wave = c/o tile
  const unsigned l15  = lane & 15u, q = lane >> 4;
  const unsigned n = blockIdx.y, t0 = blockIdx.x * 12u;

  // BN consts in registers for this lane's 4 output rows o = mt*16+q*4+r
  float ksr[4], kbr[4];
  #pragma unroll
  for (int r = 0; r < 4; ++r) {
    unsigned o = mt*16 + q*4 + (unsigned)r;
    float sc = gam[o] * rsqrtf(var[o] + 1e-5f);
    ksr[r] = sc;
    kbr[r] = (bd[o] + bd[64+o] + bd[128+o] - mu[o]) * sc + bet[o];
  }
  // att^T B-frags in registers: B[n=u][k=v]; zeros for v>=25 (kills x garbage)
  short8v ATf[3][2];
  #pragma unroll
  for (int s = 0; s < 3; ++s)
    #pragma unroll
    for (int nt2 = 0; nt2 < 2; ++nt2) {
      unsigned u = (unsigned)nt2*16 + l15;
      float tf[8];
      #pragma unroll
      for (int j = 0; j < 8; ++j) {
        unsigned v = q*8 + (unsigned)j;
        tf[j] = (v < 25 && u < 25) ? att[(((size_t)n*3 + s)*25 + v)*25 + u] : 0.f;
      }
      ATf[s][nt2] = pk8(tf);
    }
  // wd A-frags in registers: A[m=o][k=c]
  short8v Awf[6];
  #pragma unroll
  for (int ks = 0; ks < 6; ++ks) {
    const float* src = wd + ((size_t)((unsigned)ks>>1)*64 + mt*16 + l15)*64
                     + ((unsigned)ks & 1u)*32 + q*8;
    float tf[8];
    #pragma unroll
    for (int j = 0; j < 8; ++j) tf[j] = src[j];
    Awf[ks] = pk8(tf);
  }
  // residual offsets (global, o*7500+u) and obuf offsets (o*100+u)
  unsigned offs[2][4], lofs[2][4];
  const bool valid1 = (l15 < 9);                    // u=16+l15 < 25
  #pragma unroll
  for (int nt2 = 0; nt2 < 2; ++nt2)
    #pragma unroll
    for (int r = 0; r < 4; ++r) {
      unsigned o = mt*16 + q*4 + (unsigned)r;
      unsigned u = (unsigned)nt2*16 + l15;
      offs[nt2][r] = o*7500u + u;
      lofs[nt2][r] = o*100u  + u;
    }

  const float* xn = x + (size_t)n * 480000;
  float*       on = (float*)out + (size_t)n * 480000;
  const float* xr = xn + (size_t)(mt*16 + l15)*7500;   // this lane's P A-row

  // ---- prologue: P(t0) -> Pt[0] ----
  {
    const float* pa = xr + t0*25 + q*8;
    float fa[8];
    #pragma unroll
    for (int j = 0; j < 8; ++j) fa[j] = pa[j];
    short8v Ax = pk8(fa);
    #pragma unroll
    for (int s = 0; s < 3; ++s)
      #pragma unroll
      for (int nt2 = 0; nt2 < 2; ++nt2) {
        float4v d = (float4v){0.f,0.f,0.f,0.f};
        d = MFMA_BF16(Ax, ATf[s][nt2], d);
        unsigned u  = (unsigned)nt2*16 + l15;
        unsigned kb = (unsigned)s*64 + mt*16 + q*4;
        uint2 pk2; pk2.x = pack2bf(d[0], d[1]); pk2.y = pack2bf(d[2], d[3]);
        *(uint2*)(&Pt[0][u*196 + kb]) = pk2;
      }
  }

  for (unsigned t = 0; t < 12; ++t) {
    const unsigned cur = t & 1u, nxt = cur ^ 1u;
    const unsigned tg = t0 + t, t25 = tg*25;
    __syncthreads();   // P(t) visible; Z(t-1) Pt reads + prev flush obuf reads done

    // ---- next A-frag loads early (overlap Z) ----
    const bool hasnext = (t + 1u < 12u);
    short8v Axn;
    if (hasnext) {
      const float* pa = xr + t25 + 25 + q*8;
      float fa[8];
      #pragma unroll
      for (int j = 0; j < 8; ++j) fa[j] = pa[j];
      Axn = pk8(fa);
    }
    // ---- residual loads early ----
    float xv[2][4];
    #pragma unroll
    for (int nt2 = 0; nt2 < 2; ++nt2)
      if (nt2 == 0 || valid1) {
        #pragma unroll
        for (int r = 0; r < 4; ++r) xv[nt2][r] = xn[offs[nt2][r] + t25];
      }
    // ---- Z phase: Z[o][u] = sum_{s,c} wd[s][o][c]*P[s*64+c][u] ----
    float4v za = (float4v){0.f,0.f,0.f,0.f}, zb = (float4v){0.f,0.f,0.f,0.f};
    #pragma unroll
    for (int ks = 0; ks < 6; ++ks) {
      short8v B0 = ld8_b64(&Pt[cur][l15*196      + (unsigned)ks*32 + q*8]);
      short8v B1 = ld8_b64(&Pt[cur][(16+l15)*196 + (unsigned)ks*32 + q*8]);
      za = MFMA_BF16(Awf[ks], B0, za);
      zb = MFMA_BF16(Awf[ks], B1, zb);
    }
    // ---- P(t+1) -> Pt[nxt] ----
    if (hasnext) {
      #pragma unroll
      for (int s = 0; s < 3; ++s)
        #pragma unroll
        for (int nt2 = 0; nt2 < 2; ++nt2) {
          float4v d = (float4v){0.f,0.f,0.f,0.f};
          d = MFMA_BF16(Axn, ATf[s][nt2], d);
          unsigned u  = (unsigned)nt2*16 + l15;
          unsigned kb = (unsigned)s*64 + mt*16 + q*4;
          uint2 pk2; pk2.x = pack2bf(d[0], d[1]); pk2.y = pack2bf(d[2], d[3]);
          *(uint2*)(&Pt[nxt][u*196 + kb]) = pk2;
        }
    }
    // ---- epilogue: BN + fp32 residual + ReLU -> obuf (LDS) ----
    const unsigned tloc = (t & 3u)*25u;
    #pragma unroll
    for (int nt2 = 0; nt2 < 2; ++nt2) {
      float4v zz = nt2 ? zb : za;
      if (nt2 == 0 || valid1) {
        #pragma unroll
        for (int r = 0; r < 4; ++r) {
          float val = zz[r]*ksr[r] + kbr[r] + xv[nt2][r];
          obuf[lofs[nt2][r] + tloc] = fmaxf(val, 0.f);
        }
      }
    }
    // ---- flush every 4 t: contiguous 400 B per c, float4, coalesced ----
    if ((t & 3u) == 3u) {
      __syncthreads();                              // all obuf writes visible
      const unsigned tb = (t0 + (t & ~3u)) * 25u;   // chunk-start t * 25
      for (unsigned g = tid; g < 1600u; g += 256u) {
        unsigned c  = g / 25u;
        unsigned w4 = g - c*25u;
        float4v vv = *(const float4v*)&obuf[c*100u + w4*4u];
        *(float4v*)&on[(size_t)c*7500u + tb + w4*4u] = vv;
      }
    }
  }
}

// ================================ launcher ==================================
extern "C" void kernel_launch(void* const* d_in, const int* in_sizes, int n_in,
                              void* d_out, int out_size, void* d_ws, size_t ws_size,
                              hipStream_t stream)
{
  (void)in_sizes; (void)n_in; (void)out_size;
  const float* x   = (const float*)d_in[0];
  const float* A   = (const float*)d_in[1];
  const float* PA  = (const float*)d_in[2];
  const float* wa  = (const float*)d_in[3];
  const float* ba  = (const float*)d_in[4];
  const float* wb  = (const float*)d_in[5];
  const float* bb  = (const float*)d_in[6];
  const float* wd  = (const float*)d_in[7];
  const float* bd  = (const float*)d_in[8];
  const float* gam = (const float*)d_in[9];
  const float* bet = (const float*)d_in[10];
  const float* mu  = (const float*)d_in[11];
  const float* var = (const float*)d_in[12];
  float* out = (float*)d_out;

  const size_t NEED = (size_t)(25*120000 + 120000) * sizeof(float);  // 12.48 MB
  if (ws_size >= NEED) {
    // -------- partial-sum path: no atomics, no K0 --------
    float* part = (float*)d_ws;              // 25 * 64 * 1875 = 3,000,000 f32
    float* att  = part + 3000000;            // 64*3*625 = 120,000 f32
    hipLaunchKernelGGL(k1_scores, dim3(25, 64), dim3(256), 0, stream,
                       x, wa, ba, wb, bb, part, part, 0);
    hipLaunchKernelGGL(k2_softmax_r, dim3(3, 64), dim3(256), 0, stream,
                       part, A, PA, att);
    hipLaunchKernelGGL(k3_main, dim3(25, 64), dim3(256), 0, stream,
                       x, wd, bd, gam, bet, mu, var, att, out);
  } else {
    // -------- fallback: verified atomic path --------
    float* scores = (float*)d_ws;            // 120,000 f32
    float* att    = scores + 120000;         // 120,000 f32
    hipLaunchKernelGGL(k0_zero, dim3((120000 + 255)/256), dim3(256), 0, stream,
                       scores, 120000);
    hipLaunchKernelGGL(k1_scores, dim3(25, 64), dim3(256), 0, stream,
                       x, wa, ba, wb, bb, scores, scores, 1);
    hipLaunchKernelGGL(k2_softmax, dim3(3, 64), dim3(64), 0, stream,
                       scores, A, PA, att);
    hipLaunchKernelGGL(k3_main, dim3(25, 64), dim3(256), 0, stream,
                       x, wd, bd, gam, bet, mu, var, att, out);
  }
}